// Round 6
// baseline (37440.814 us; speedup 1.0000x reference)
//
#include <hip/hip_runtime.h>

typedef __bf16 bf16x8  __attribute__((ext_vector_type(8)));
typedef float  f32x4   __attribute__((ext_vector_type(4)));

#define MFMA16(a,b,c) __builtin_amdgcn_mfma_f32_16x16x32_bf16((a),(b),(c),0,0,0)

constexpr int BB = 128, TT = 512, II = 512, HH = 1024, OO = 512;
constexpr int TICKS = TT + 4;     // 4 layer stages + FC lag
constexpr int LDS_BYTES = 81920;  // stage0: 16K wih0 + 32K whh0 + 32K wfc

// -------- workspace layout (bytes) --------
constexpr size_t HB_BYTES = (size_t)2*4*BB*HH*2;              // 2 MiB
constexpr size_t C1_OFF   = HB_BYTES;
constexpr size_t C1_BYTES = (size_t)TICKS*8*64;
constexpr size_t C2_OFF   = C1_OFF + C1_BYTES;
constexpr size_t C2_BYTES = (size_t)TICKS*64;
constexpr size_t CNT_END  = C2_OFF + C2_BYTES;                // ~2.3 MiB

__device__ __forceinline__ float tanh_fast(float v) {
    float e = __expf(2.0f * v);
    return 1.0f - 2.0f / (e + 1.0f);
}

__device__ __forceinline__ bf16x8 cvt8(const float* __restrict__ p) {
    float4 a = *(const float4*)p;
    float4 b = *(const float4*)(p + 4);
    bf16x8 r;
    r[0]=(__bf16)a.x; r[1]=(__bf16)a.y; r[2]=(__bf16)a.z; r[3]=(__bf16)a.w;
    r[4]=(__bf16)b.x; r[5]=(__bf16)b.y; r[6]=(__bf16)b.z; r[7]=(__bf16)b.w;
    return r;
}
__device__ __forceinline__ bf16x8 ldfrag(const __bf16* __restrict__ p) {
    return *(const bf16x8*)p;
}
__device__ __forceinline__ bf16x8 ldfrag(const float* __restrict__ p) {
    return cvt8(p);
}

// Stage a weight slice (16 cols, K = Kdim) from f32 global into an LDS
// "fragment image": chunk c = (k-iter i)*64 + lane is the 16B lane reads at
// iteration i -> per-tick ds_read_b128 is lane-contiguous, conflict-free.
__device__ __forceinline__ void stage_img(char* dst, const float* __restrict__ W,
                                          int Kdim, int col0, int tid) {
    const int nch = (Kdim / 32) * 64;
    for (int c = tid; c < nch; c += 256) {
        int i  = c >> 6, ln = c & 63;
        int col = col0 + (ln & 15);
        int k0  = i * 32 + ((ln >> 4) << 3);
        bf16x8 v = cvt8(W + (size_t)col * Kdim + k0);
        *(bf16x8*)(dst + (size_t)c * 16) = v;
    }
}

// Register-staged K-sweep: per chunk of CH iterations, issue CH ds_reads +
// 2*CH global loads (all independent, in flight together), then 2*CH MFMAs.
// MFMA order identical to the unchunked version -> bit-identical results.
template<int NITER, int CH, class TA>
__device__ __forceinline__ void gemm_img(const TA* __restrict__ a0p,
                                         const TA* __restrict__ a1p,
                                         const char* bimg, int lane,
                                         f32x4& acc0, f32x4& acc1) {
    const char* bp = bimg + (size_t)lane * 16;
    #pragma unroll 1
    for (int c = 0; c < NITER / CH; ++c) {
        bf16x8 B[CH], A0[CH], A1[CH];
        #pragma unroll
        for (int j = 0; j < CH; ++j)
            B[j] = *(const bf16x8*)(bp + (size_t)(c*CH + j) * 1024);
        #pragma unroll
        for (int j = 0; j < CH; ++j) {
            A0[j] = ldfrag(a0p + (c*CH + j) * 32);
            A1[j] = ldfrag(a1p + (c*CH + j) * 32);
        }
        #pragma unroll
        for (int j = 0; j < CH; ++j) {
            acc0 = MFMA16(A0[j], B[j], acc0);
            acc1 = MFMA16(A1[j], B[j], acc1);
        }
    }
}

template<int NITER, int CH>
__device__ __forceinline__ void gemm_img1(const __bf16* __restrict__ ap,
                                          const char* bimg, int lane, f32x4& acc) {
    const char* bp = bimg + (size_t)lane * 16;
    #pragma unroll 1
    for (int c = 0; c < NITER / CH; ++c) {
        bf16x8 B[CH], A[CH];
        #pragma unroll
        for (int j = 0; j < CH; ++j)
            B[j] = *(const bf16x8*)(bp + (size_t)(c*CH + j) * 1024);
        #pragma unroll
        for (int j = 0; j < CH; ++j)
            A[j] = *(const bf16x8*)(ap + (c*CH + j) * 32);
        #pragma unroll
        for (int j = 0; j < CH; ++j)
            acc = MFMA16(A[j], B[j], acc);
    }
}

// Two-level tick-indexed grid barrier (counters zeroed by host memset; each
// tick uses fresh counters -> no reuse/reset races).
__device__ __forceinline__ void grid_barrier(char* wsb, int tk, int grp, int tid) {
    __threadfence();                 // release: drain this wave's h stores
    __syncthreads();                 // all waves of block have fenced
    if (tid == 0) {
        int* c1 = (int*)(wsb + C1_OFF + ((size_t)tk * 8 + grp) * 64);
        int* c2 = (int*)(wsb + C2_OFF + (size_t)tk * 64);
        int v = __hip_atomic_fetch_add(c1, 1, __ATOMIC_ACQ_REL, __HIP_MEMORY_SCOPE_AGENT);
        if (v == 31)
            __hip_atomic_fetch_add(c2, 1, __ATOMIC_ACQ_REL, __HIP_MEMORY_SCOPE_AGENT);
        while (__hip_atomic_load(c2, __ATOMIC_RELAXED, __HIP_MEMORY_SCOPE_AGENT) < 8)
            __builtin_amdgcn_s_sleep(2);
    }
    __syncthreads();
    __threadfence();                 // acquire: invalidate stale L1/L2
}

__global__ void __launch_bounds__(256, 1)
rnn_coop(const float* __restrict__ x,
         const float* __restrict__ W_ih0, const float* __restrict__ b_ih0,
         const float* __restrict__ W_hh0, const float* __restrict__ b_hh0,
         const float* __restrict__ W_ih,  const float* __restrict__ b_ih,
         const float* __restrict__ W_hh,  const float* __restrict__ b_hh,
         const float* __restrict__ W_fc,  const float* __restrict__ b_fc,
         float* __restrict__ out, char* __restrict__ wsb)
{
    extern __shared__ char smem[];
    const int blk = blockIdx.x, tid = threadIdx.x;
    const int wave = tid >> 6, lane = tid & 63;
    const int lrow = lane & 15;
    const int kg8  = (lane >> 4) << 3;
    const int rb   = (lane >> 4) << 2;

    const int xcd   = blk & 7;
    const int stage = xcd >> 1;                       // 0..3
    const int tile  = (blk >> 3) | ((xcd & 1) << 5);  // 0..63 within stage
    const int N0    = tile * 16;                      // 16 output cols per block

    // ---- one-time: stage this block's weight slices into LDS ----
    // stage0 : wih0 img @0 (16K) | whh0 img @16K (32K) | wfc img @48K (32K)
    // stage>0: wih  img @0 (32K) | whh  img @32K (32K)
    char* img_a = smem;
    char* img_b;
    char* img_fc = smem + 49152;
    if (stage == 0) {
        img_b = smem + 16384;
        stage_img(img_a, W_ih0, II, N0, tid);
        stage_img(img_b, W_hh0, HH, N0, tid);
        stage_img(img_fc, W_fc, HH, (tile & 31) * 16, tid);
    } else {
        img_b = smem + 32768;
        stage_img(img_a, W_ih + (size_t)(stage-1)*HH*HH, HH, N0, tid);
        stage_img(img_b, W_hh + (size_t)(stage-1)*HH*HH, HH, N0, tid);
    }

    // ---- per-thread constants ----
    const int bcol = N0 + lrow;                 // this thread's output col
    float bi;
    if (stage == 0) bi = b_ih0[bcol] + b_hh0[bcol];
    else            bi = b_ih[(stage-1)*HH + bcol] + b_hh[(stage-1)*HH + bcol];

    // FC duty (64 stage-0 blocks): 64 rows x 16 cols each
    const int fcol  = (tile & 31) * 16 + lrow;
    const int frow0 = (tile >> 5) * 64 + 16 * wave;   // this wave's 16 FC rows
    const float fbias = (stage == 0) ? b_fc[fcol] : 0.f;

    const int r0 = 32 * wave + lrow;            // A-row for M-frag 0
    __bf16* hb = (__bf16*)wsb;

    __syncthreads();   // LDS images ready (block-local data only before tick 0)

    // ---- pipelined tick loop ----
    for (int tk = 0; tk < TICKS; ++tk) {
        const int p = (tk + 1) & 1;             // read parity
        const int q = tk & 1;                   // write parity
        const int t = tk - stage;

        if (t >= 0 && t < TT) {
            f32x4 acc0 = {0.f,0.f,0.f,0.f};
            f32x4 acc1 = {0.f,0.f,0.f,0.f};
            if (stage == 0) {
                const float* xa0 = x + (size_t)r0 * (TT*II) + (size_t)t * II + kg8;
                gemm_img<II/32, 4>(xa0, xa0 + (size_t)16*(TT*II), img_a, lane, acc0, acc1);
                const __bf16* ha = hb + ((size_t)(p*4 + 0) * BB + r0) * HH + kg8;
                gemm_img<HH/32, 8>(ha, ha + 16*HH, img_b, lane, acc0, acc1);
            } else {
                const __bf16* a1 = hb + ((size_t)(p*4 + stage-1) * BB + r0) * HH + kg8;
                gemm_img<HH/32, 8>(a1, a1 + 16*HH, img_a, lane, acc0, acc1);
                const __bf16* a2 = hb + ((size_t)(p*4 + stage) * BB + r0) * HH + kg8;
                gemm_img<HH/32, 8>(a2, a2 + 16*HH, img_b, lane, acc0, acc1);
            }
            __bf16* hq = hb + (size_t)(q*4 + stage) * (BB*HH);
            #pragma unroll
            for (int j = 0; j < 4; ++j) {
                int m = 32 * wave + rb + j;
                hq[(size_t)m*HH + bcol]        = (__bf16)tanh_fast(acc0[j] + bi);
                hq[(size_t)(m+16)*HH + bcol]   = (__bf16)tanh_fast(acc1[j] + bi);
            }
        }

        if (stage == 0) {
            const int t4 = tk - 4;
            if (t4 >= 0) {
                f32x4 fa = {0.f,0.f,0.f,0.f};
                const __bf16* ap = hb + ((size_t)(p*4 + 3) * BB + frow0 + lrow) * HH + kg8;
                gemm_img1<HH/32, 8>(ap, img_fc, lane, fa);
                #pragma unroll
                for (int j = 0; j < 4; ++j) {
                    int b = frow0 + rb + j;
                    // nontemporal: keep out-stores out of the per-tick L2
                    // writeback set (out is never read by the kernel)
                    __builtin_nontemporal_store(fa[j] + fbias,
                        &out[((size_t)b*TT + t4)*OO + fcol]);
                }
            }
        }

        grid_barrier(wsb, tk, xcd, tid);
    }
}

extern "C" void kernel_launch(void* const* d_in, const int* in_sizes, int n_in,
                              void* d_out, int out_size, void* d_ws, size_t ws_size,
                              hipStream_t stream) {
    const float* x     = (const float*)d_in[0];
    const float* W_ih0 = (const float*)d_in[1];
    const float* b_ih0 = (const float*)d_in[2];
    const float* W_hh0 = (const float*)d_in[3];
    const float* b_hh0 = (const float*)d_in[4];
    const float* W_ih  = (const float*)d_in[5];
    const float* b_ih  = (const float*)d_in[6];
    const float* W_hh  = (const float*)d_in[7];
    const float* b_hh  = (const float*)d_in[8];
    const float* W_fc  = (const float*)d_in[9];
    const float* b_fc  = (const float*)d_in[10];
    float* outp = (float*)d_out;
    char*  wsp  = (char*)d_ws;

    if (ws_size < CNT_END) return;   // diagnostic gate (would show stub error)

    // allow 80 KB dynamic LDS (default cap is 64 KB)
    static int lds_attr_set = 0;     // host-side only; idempotent
    if (!lds_attr_set) {
        hipFuncSetAttribute((const void*)rnn_coop,
                            hipFuncAttributeMaxDynamicSharedMemorySize, LDS_BYTES);
        lds_attr_set = 1;
    }

    // zero h double-buffer + all barrier counters (tick-indexed, used once each)
    hipMemsetAsync(d_ws, 0, CNT_END, stream);

    void* args[] = { &x, &W_ih0, &b_ih0, &W_hh0, &b_hh0,
                     &W_ih, &b_ih, &W_hh, &b_hh, &W_fc, &b_fc,
                     &outp, &wsp };
    hipLaunchCooperativeKernel((const void*)rnn_coop, dim3(256), dim3(256),
                               args, LDS_BYTES, stream);
}

// Round 7
// 11426.231 us; speedup vs baseline: 3.2767x; 3.2767x over previous
//
#include <hip/hip_runtime.h>

typedef __bf16 bf16x8  __attribute__((ext_vector_type(8)));
typedef float  f32x4   __attribute__((ext_vector_type(4)));

#define MFMA16(a,b,c) __builtin_amdgcn_mfma_f32_16x16x32_bf16((a),(b),(c),0,0,0)

constexpr int BB = 128, TT = 512, II = 512, HH = 1024, OO = 512;
constexpr int TICKS = TT + 4;     // 4 layer stages + FC lag
constexpr int LDS_BYTES = 81920;  // stage0: 16K wih0 + 32K whh0 + 32K wfc

// -------- workspace layout (bytes) --------
constexpr size_t HB_BYTES = (size_t)2*4*BB*HH*2;            // 2 MiB h dbuf
constexpr size_t AF_OFF   = HB_BYTES;                       // [TICKS][8][64] arrival flags
constexpr size_t AF_BYTES = (size_t)TICKS*8*64*4;
constexpr size_t XF_OFF   = AF_OFF + AF_BYTES;              // [TICKS] 64B line (8 ints)
constexpr size_t XF_BYTES = (size_t)TICKS*64;
constexpr size_t GO_OFF   = XF_OFF + XF_BYTES;              // [TICKS][8] 64B lines
constexpr size_t GO_BYTES = (size_t)TICKS*8*64;
constexpr size_t CE_OFF   = GO_OFF + GO_BYTES;              // census[8] ints
constexpr size_t CE_BYTES = 64;
constexpr size_t IB_OFF   = CE_OFF + CE_BYTES;              // init barrier c1[8]+c2
constexpr size_t IB_BYTES = 9*64;
constexpr size_t CNT_END  = IB_OFF + IB_BYTES;              // ~3.4 MiB

__device__ __forceinline__ float tanh_fast(float v) {
    float e = __expf(2.0f * v);
    return 1.0f - 2.0f / (e + 1.0f);
}

__device__ __forceinline__ bf16x8 cvt8(const float* __restrict__ p) {
    float4 a = *(const float4*)p;
    float4 b = *(const float4*)(p + 4);
    bf16x8 r;
    r[0]=(__bf16)a.x; r[1]=(__bf16)a.y; r[2]=(__bf16)a.z; r[3]=(__bf16)a.w;
    r[4]=(__bf16)b.x; r[5]=(__bf16)b.y; r[6]=(__bf16)b.z; r[7]=(__bf16)b.w;
    return r;
}
__device__ __forceinline__ bf16x8 ldfrag(const __bf16* __restrict__ p) {
    return *(const bf16x8*)p;
}
__device__ __forceinline__ bf16x8 ldfrag(const float* __restrict__ p) {
    return cvt8(p);
}

__device__ __forceinline__ void stage_img(char* dst, const float* __restrict__ W,
                                          int Kdim, int col0, int tid) {
    const int nch = (Kdim / 32) * 64;
    for (int c = tid; c < nch; c += 256) {
        int i  = c >> 6, ln = c & 63;
        int col = col0 + (ln & 15);
        int k0  = i * 32 + ((ln >> 4) << 3);
        bf16x8 v = cvt8(W + (size_t)col * Kdim + k0);
        *(bf16x8*)(dst + (size_t)c * 16) = v;
    }
}

template<int NITER, int CH, class TA>
__device__ __forceinline__ void gemm_img(const TA* __restrict__ a0p,
                                         const TA* __restrict__ a1p,
                                         const char* bimg, int lane,
                                         f32x4& acc0, f32x4& acc1) {
    const char* bp = bimg + (size_t)lane * 16;
    #pragma unroll 1
    for (int c = 0; c < NITER / CH; ++c) {
        bf16x8 B[CH], A0[CH], A1[CH];
        #pragma unroll
        for (int j = 0; j < CH; ++j)
            B[j] = *(const bf16x8*)(bp + (size_t)(c*CH + j) * 1024);
        #pragma unroll
        for (int j = 0; j < CH; ++j) {
            A0[j] = ldfrag(a0p + (c*CH + j) * 32);
            A1[j] = ldfrag(a1p + (c*CH + j) * 32);
        }
        #pragma unroll
        for (int j = 0; j < CH; ++j) {
            acc0 = MFMA16(A0[j], B[j], acc0);
            acc1 = MFMA16(A1[j], B[j], acc1);
        }
    }
}

template<int NITER, int CH>
__device__ __forceinline__ void gemm_img1(const __bf16* __restrict__ ap,
                                          const char* bimg, int lane, f32x4& acc) {
    const char* bp = bimg + (size_t)lane * 16;
    #pragma unroll 1
    for (int c = 0; c < NITER / CH; ++c) {
        bf16x8 B[CH], A[CH];
        #pragma unroll
        for (int j = 0; j < CH; ++j)
            B[j] = *(const bf16x8*)(bp + (size_t)(c*CH + j) * 1024);
        #pragma unroll
        for (int j = 0; j < CH; ++j)
            A[j] = *(const bf16x8*)(ap + (c*CH + j) * 32);
        #pragma unroll
        for (int j = 0; j < CH; ++j)
            acc = MFMA16(A[j], B[j], acc);
    }
}

// ---- one-time heavy init barrier (R5-proven pattern, fresh counters) ----
__device__ __forceinline__ void init_barrier(char* wsb, int grp, int tid) {
    __threadfence();
    __syncthreads();
    if (tid == 0) {
        int* c1 = (int*)(wsb + IB_OFF + (size_t)grp * 64);
        int* c2 = (int*)(wsb + IB_OFF + 8 * 64);
        int v = __hip_atomic_fetch_add(c1, 1, __ATOMIC_ACQ_REL, __HIP_MEMORY_SCOPE_AGENT);
        if (v == 31)
            __hip_atomic_fetch_add(c2, 1, __ATOMIC_ACQ_REL, __HIP_MEMORY_SCOPE_AGENT);
        while (__hip_atomic_load(c2, __ATOMIC_RELAXED, __HIP_MEMORY_SCOPE_AGENT) < 8)
            __builtin_amdgcn_s_sleep(2);
    }
    __syncthreads();
    __threadfence();
}

// ---- per-tick hierarchical barrier: 1 wbl2 + 1 inv(L2) per XCD per tick ----
__device__ __forceinline__ void tick_sync(char* wsb, int tk, int myxcd,
                                          int slot, int nblk, unsigned xmask,
                                          int tid) {
    __syncthreads();   // implicit vmcnt(0): all waves' h/out stores are in L2
    int* af = (int*)(wsb + AF_OFF) + ((size_t)tk * 8 + myxcd) * 64;
    int* xf = (int*)(wsb + XF_OFF + (size_t)tk * 64);
    int* go = (int*)(wsb + GO_OFF + ((size_t)tk * 8 + myxcd) * 64);
    if (tid < 64) {
        if (slot == 0) {
            // wait local arrivals (slots 1..nblk-1); lane L polls slot L
            for (;;) {
                int v = (tid >= 1 && tid < nblk)
                      ? __hip_atomic_load(af + tid, __ATOMIC_RELAXED, __HIP_MEMORY_SCOPE_AGENT)
                      : 1;
                if (__all(v != 0)) break;
            }
            // single L2 writeback for this XCD (pushes all blocks' h stores)
            asm volatile("buffer_wbl2 sc1\n\ts_waitcnt vmcnt(0)" ::: "memory");
            if (tid == 0)
                __hip_atomic_store(xf + myxcd, 1, __ATOMIC_RELAXED, __HIP_MEMORY_SCOPE_AGENT);
            // wait all (non-empty) XCDs' writebacks
            for (;;) {
                int v = (tid < 8 && (xmask >> tid) & 1)
                      ? __hip_atomic_load(xf + tid, __ATOMIC_RELAXED, __HIP_MEMORY_SCOPE_AGENT)
                      : 1;
                if (__all(v != 0)) break;
                __builtin_amdgcn_s_sleep(1);
            }
            // single L2(+L1) invalidate for this XCD, then release local blocks
            asm volatile("buffer_inv sc1\n\ts_waitcnt vmcnt(0)" ::: "memory");
            if (tid == 0)
                __hip_atomic_store(go, 1, __ATOMIC_RELAXED, __HIP_MEMORY_SCOPE_AGENT);
        } else {
            if (tid == 0)
                __hip_atomic_store(af + slot, 1, __ATOMIC_RELAXED, __HIP_MEMORY_SCOPE_AGENT);
            for (;;) {
                int v = __hip_atomic_load(go, __ATOMIC_RELAXED, __HIP_MEMORY_SCOPE_AGENT);
                if (__all(v != 0)) break;
                __builtin_amdgcn_s_sleep(1);
            }
            // CU-local L1 invalidate (L2 already inv'd by slot-0 block)
            asm volatile("buffer_inv sc0\n\ts_waitcnt vmcnt(0)" ::: "memory");
        }
    }
    __syncthreads();
}

__global__ void __launch_bounds__(256, 1)
rnn_coop(const float* __restrict__ x,
         const float* __restrict__ W_ih0, const float* __restrict__ b_ih0,
         const float* __restrict__ W_hh0, const float* __restrict__ b_hh0,
         const float* __restrict__ W_ih,  const float* __restrict__ b_ih,
         const float* __restrict__ W_hh,  const float* __restrict__ b_hh,
         const float* __restrict__ W_fc,  const float* __restrict__ b_fc,
         float* __restrict__ out, char* __restrict__ wsb)
{
    extern __shared__ char smem[];
    __shared__ int sh_slot, sh_n;
    __shared__ unsigned sh_mask;

    const int blk = blockIdx.x, tid = threadIdx.x;
    const int wave = tid >> 6, lane = tid & 63;
    const int lrow = lane & 15;
    const int kg8  = (lane >> 4) << 3;
    const int rb   = (lane >> 4) << 2;

    // physical XCD id (stable for block lifetime) — correctness-grade grouping
    int myxcd;
    asm volatile("s_getreg_b32 %0, hwreg(HW_REG_XCC_ID)" : "=s"(myxcd));
    myxcd &= 7;

    // census: unique slot within this physical XCD
    if (tid == 0)
        sh_slot = __hip_atomic_fetch_add((int*)(wsb + CE_OFF) + myxcd, 1,
                                         __ATOMIC_RELAXED, __HIP_MEMORY_SCOPE_AGENT);

    // work mapping (deterministic, independent of physical placement)
    const int stage = (blk & 7) >> 1;                       // 0..3
    const int tile  = (blk >> 3) | ((blk & 1) << 5);        // 0..63 within stage
    const int N0    = tile * 16;

    // ---- one-time: stage weight slices into LDS fragment images ----
    char* img_a = smem;
    char* img_b;
    char* img_fc = smem + 49152;
    if (stage == 0) {
        img_b = smem + 16384;
        stage_img(img_a, W_ih0, II, N0, tid);
        stage_img(img_b, W_hh0, HH, N0, tid);
        stage_img(img_fc, W_fc, HH, (tile & 31) * 16, tid);
    } else {
        img_b = smem + 32768;
        stage_img(img_a, W_ih + (size_t)(stage-1)*HH*HH, HH, N0, tid);
        stage_img(img_b, W_hh + (size_t)(stage-1)*HH*HH, HH, N0, tid);
    }

    const int bcol = N0 + lrow;
    float bi;
    if (stage == 0) bi = b_ih0[bcol] + b_hh0[bcol];
    else            bi = b_ih[(stage-1)*HH + bcol] + b_hh[(stage-1)*HH + bcol];

    const int fcol  = (tile & 31) * 16 + lrow;
    const int frow0 = (tile >> 5) * 64 + 16 * wave;
    const float fbias = (stage == 0) ? b_fc[fcol] : 0.f;

    const int r0 = 32 * wave + lrow;
    __bf16* hb = (__bf16*)wsb;

    __syncthreads();                 // LDS images + census slot written
    init_barrier(wsb, blk & 7, tid); // census complete grid-wide

    if (tid < 64) {
        int c = (tid < 8)
              ? __hip_atomic_load((int*)(wsb + CE_OFF) + tid, __ATOMIC_RELAXED,
                                  __HIP_MEMORY_SCOPE_AGENT) : 0;
        unsigned long long b = __ballot(c > 0);
        if (tid == 0) {
            sh_mask = (unsigned)(b & 0xffu);
            sh_n = __hip_atomic_load((int*)(wsb + CE_OFF) + myxcd, __ATOMIC_RELAXED,
                                     __HIP_MEMORY_SCOPE_AGENT);
        }
    }
    __syncthreads();
    const int slot = sh_slot, nblk = sh_n;
    const unsigned xmask = sh_mask;

    // ---- pipelined tick loop ----
    for (int tk = 0; tk < TICKS; ++tk) {
        const int p = (tk + 1) & 1;             // read parity
        const int q = tk & 1;                   // write parity
        const int t = tk - stage;

        if (t >= 0 && t < TT) {
            f32x4 acc0 = {0.f,0.f,0.f,0.f};
            f32x4 acc1 = {0.f,0.f,0.f,0.f};
            if (stage == 0) {
                const float* xa0 = x + (size_t)r0 * (TT*II) + (size_t)t * II + kg8;
                gemm_img<II/32, 4>(xa0, xa0 + (size_t)16*(TT*II), img_a, lane, acc0, acc1);
                const __bf16* ha = hb + ((size_t)(p*4 + 0) * BB + r0) * HH + kg8;
                gemm_img<HH/32, 8>(ha, ha + 16*HH, img_b, lane, acc0, acc1);
            } else {
                const __bf16* a1 = hb + ((size_t)(p*4 + stage-1) * BB + r0) * HH + kg8;
                gemm_img<HH/32, 8>(a1, a1 + 16*HH, img_a, lane, acc0, acc1);
                const __bf16* a2 = hb + ((size_t)(p*4 + stage) * BB + r0) * HH + kg8;
                gemm_img<HH/32, 8>(a2, a2 + 16*HH, img_b, lane, acc0, acc1);
            }
            __bf16* hq = hb + (size_t)(q*4 + stage) * (BB*HH);
            #pragma unroll
            for (int j = 0; j < 4; ++j) {
                int m = 32 * wave + rb + j;
                hq[(size_t)m*HH + bcol]        = (__bf16)tanh_fast(acc0[j] + bi);
                hq[(size_t)(m+16)*HH + bcol]   = (__bf16)tanh_fast(acc1[j] + bi);
            }
        }

        if (stage == 0) {
            const int t4 = tk - 4;
            if (t4 >= 0) {
                f32x4 fa = {0.f,0.f,0.f,0.f};
                const __bf16* ap = hb + ((size_t)(p*4 + 3) * BB + frow0 + lrow) * HH + kg8;
                gemm_img1<HH/32, 8>(ap, img_fc, lane, fa);
                #pragma unroll
                for (int j = 0; j < 4; ++j) {
                    int b = frow0 + rb + j;
                    __builtin_nontemporal_store(fa[j] + fbias,
                        &out[((size_t)b*TT + t4)*OO + fcol]);
                }
            }
        }

        if (tk < TICKS - 1)
            tick_sync(wsb, tk, myxcd, slot, nblk, xmask, tid);
    }
}

extern "C" void kernel_launch(void* const* d_in, const int* in_sizes, int n_in,
                              void* d_out, int out_size, void* d_ws, size_t ws_size,
                              hipStream_t stream) {
    const float* x     = (const float*)d_in[0];
    const float* W_ih0 = (const float*)d_in[1];
    const float* b_ih0 = (const float*)d_in[2];
    const float* W_hh0 = (const float*)d_in[3];
    const float* b_hh0 = (const float*)d_in[4];
    const float* W_ih  = (const float*)d_in[5];
    const float* b_ih  = (const float*)d_in[6];
    const float* W_hh  = (const float*)d_in[7];
    const float* b_hh  = (const float*)d_in[8];
    const float* W_fc  = (const float*)d_in[9];
    const float* b_fc  = (const float*)d_in[10];
    float* outp = (float*)d_out;
    char*  wsp  = (char*)d_ws;

    if (ws_size < CNT_END) return;   // diagnostic gate

    static int lds_attr_set = 0;     // host-side only; idempotent
    if (!lds_attr_set) {
        hipFuncSetAttribute((const void*)rnn_coop,
                            hipFuncAttributeMaxDynamicSharedMemorySize, LDS_BYTES);
        lds_attr_set = 1;
    }

    // zero h double-buffer + all flags/counters (tick-indexed, used once each)
    hipMemsetAsync(d_ws, 0, CNT_END, stream);

    void* args[] = { &x, &W_ih0, &b_ih0, &W_hh0, &b_hh0,
                     &W_ih, &b_ih, &W_hh, &b_hh, &W_fc, &b_fc,
                     &outp, &wsp };
    hipLaunchCooperativeKernel((const void*)rnn_coop, dim3(256), dim3(256),
                               args, LDS_BYTES, stream);
}

// Round 8
// 10001.679 us; speedup vs baseline: 3.7435x; 1.1424x over previous
//
#include <hip/hip_runtime.h>

typedef __bf16 bf16x8  __attribute__((ext_vector_type(8)));
typedef float  f32x4   __attribute__((ext_vector_type(4)));

#define MFMA16(a,b,c) __builtin_amdgcn_mfma_f32_16x16x32_bf16((a),(b),(c),0,0,0)

constexpr int BB = 128, TT = 512, II = 512, HH = 1024, OO = 512;
constexpr int TICKS = TT + 4;     // 4 layer stages + FC lag
constexpr int LDS_BYTES = 81920;  // stage0: 16K wih0 + 32K whh0 + 32K wfc
constexpr int NBLK = 256;

// -------- workspace layout (bytes) --------
constexpr size_t HB_BYTES = (size_t)2*4*BB*HH*2;            // 2 MiB h dbuf
constexpr size_t AF_OFF   = HB_BYTES;                       // [TICKS][256] int arrival flags
constexpr size_t AF_BYTES = (size_t)TICKS*NBLK*4;
constexpr size_t GO_OFF   = AF_OFF + AF_BYTES;              // [TICKS][8] 64B go lines
constexpr size_t GO_BYTES = (size_t)TICKS*8*64;
constexpr size_t CE_OFF   = GO_OFF + GO_BYTES;              // census[8]
constexpr size_t CE_BYTES = 64;
constexpr size_t IB_OFF   = CE_OFF + CE_BYTES;              // init barrier c1[8]+c2
constexpr size_t IB_BYTES = 9*64;
constexpr size_t CNT_END  = IB_OFF + IB_BYTES;

__device__ __forceinline__ float tanh_fast(float v) {
    float e = __expf(2.0f * v);
    return 1.0f - 2.0f / (e + 1.0f);
}

__device__ __forceinline__ bf16x8 cvt8(const float* __restrict__ p) {
    float4 a = *(const float4*)p;
    float4 b = *(const float4*)(p + 4);
    bf16x8 r;
    r[0]=(__bf16)a.x; r[1]=(__bf16)a.y; r[2]=(__bf16)a.z; r[3]=(__bf16)a.w;
    r[4]=(__bf16)b.x; r[5]=(__bf16)b.y; r[6]=(__bf16)b.z; r[7]=(__bf16)b.w;
    return r;
}
__device__ __forceinline__ bf16x8 ldfrag(const __bf16* __restrict__ p) {
    return *(const bf16x8*)p;
}
__device__ __forceinline__ bf16x8 ldfrag(const float* __restrict__ p) {
    return cvt8(p);
}

// write-through system-scope stores (land in coherent L3; L2 never dirty)
__device__ __forceinline__ void store_h_wt(__bf16* p, float v) {
    __bf16 b = (__bf16)v;
    unsigned u = *(unsigned short*)&b;
    asm volatile("global_store_short %0, %1, off sc0 sc1" :: "v"(p), "v"(u) : "memory");
}
__device__ __forceinline__ void store_f_wt(float* p, float v) {
    asm volatile("global_store_dword %0, %1, off sc0 sc1" :: "v"(p), "v"(v) : "memory");
}

__device__ __forceinline__ void stage_img(char* dst, const float* __restrict__ W,
                                          int Kdim, int col0, int tid) {
    const int nch = (Kdim / 32) * 64;
    for (int c = tid; c < nch; c += 512) {
        int i  = c >> 6, ln = c & 63;
        int col = col0 + (ln & 15);
        int k0  = i * 32 + ((ln >> 4) << 3);
        bf16x8 v = cvt8(W + (size_t)col * Kdim + k0);
        *(bf16x8*)(dst + (size_t)c * 16) = v;
    }
}

// single-A-stream K-sweep; sched_group_barrier pins DS/VMEM/MFMA clusters so
// CH loads stay in flight per chunk.
template<int NITER, int CH, class TA>
__device__ __forceinline__ void gemm1(const TA* __restrict__ ap,
                                      const char* bimg, int lane, f32x4& acc) {
    const char* bp = bimg + (size_t)lane * 16;
    #pragma unroll 1
    for (int c = 0; c < NITER / CH; ++c) {
        bf16x8 B[CH], A[CH];
        #pragma unroll
        for (int j = 0; j < CH; ++j)
            B[j] = *(const bf16x8*)(bp + (size_t)(c*CH + j) * 1024);
        #pragma unroll
        for (int j = 0; j < CH; ++j)
            A[j] = ldfrag(ap + (c*CH + j) * 32);
        #pragma unroll
        for (int j = 0; j < CH; ++j)
            acc = MFMA16(A[j], B[j], acc);
        __builtin_amdgcn_sched_group_barrier(0x100, CH, 0);                       // DS_READ
        __builtin_amdgcn_sched_group_barrier(0x020, (sizeof(TA)==4?2*CH:CH), 0);  // VMEM_READ
        __builtin_amdgcn_sched_group_barrier(0x008, CH, 0);                       // MFMA
    }
}

// ---- one-time heavy init barrier (R5-proven pattern, fresh counters) ----
__device__ __forceinline__ void init_barrier(char* wsb, int grp, int tid) {
    __threadfence();
    __syncthreads();
    if (tid == 0) {
        int* c1 = (int*)(wsb + IB_OFF + (size_t)grp * 64);
        int* c2 = (int*)(wsb + IB_OFF + 8 * 64);
        int v = __hip_atomic_fetch_add(c1, 1, __ATOMIC_ACQ_REL, __HIP_MEMORY_SCOPE_AGENT);
        if (v == 31)
            __hip_atomic_fetch_add(c2, 1, __ATOMIC_ACQ_REL, __HIP_MEMORY_SCOPE_AGENT);
        while (__hip_atomic_load(c2, __ATOMIC_RELAXED, __HIP_MEMORY_SCOPE_AGENT) < 8)
            __builtin_amdgcn_s_sleep(2);
    }
    __syncthreads();
    __threadfence();
}

// ---- per-tick barrier: pure flags + 1 L2 tag-invalidate per XCD ----
// (all data stores are write-through -> L2 holds nothing dirty -> no wbl2)
__device__ __forceinline__ void tick_sync(char* wsb, int tk, int blk, int myxcd,
                                          bool leader, int tid) {
    __syncthreads();   // implicit vmcnt(0): all waves' WT stores acked at L3
    int* af = (int*)(wsb + AF_OFF) + (size_t)tk * NBLK;
    int* go = (int*)(wsb + GO_OFF + ((size_t)tk * 8 + myxcd) * 64);
    if (tid == 0)
        __hip_atomic_store(af + blk, 1, __ATOMIC_RELAXED, __HIP_MEMORY_SCOPE_AGENT);
    if (tid < 64) {
        if (leader) {
            for (;;) {   // wait all 256 arrivals (4 flags/lane)
                int v0 = __hip_atomic_load(af + tid,       __ATOMIC_RELAXED, __HIP_MEMORY_SCOPE_AGENT);
                int v1 = __hip_atomic_load(af + tid + 64,  __ATOMIC_RELAXED, __HIP_MEMORY_SCOPE_AGENT);
                int v2 = __hip_atomic_load(af + tid + 128, __ATOMIC_RELAXED, __HIP_MEMORY_SCOPE_AGENT);
                int v3 = __hip_atomic_load(af + tid + 192, __ATOMIC_RELAXED, __HIP_MEMORY_SCOPE_AGENT);
                if (__all(v0 && v1 && v2 && v3)) break;
                __builtin_amdgcn_s_sleep(1);
            }
            // whole-XCD L2 (+this CU's L1) tag invalidate; nothing dirty
            asm volatile("buffer_inv sc0 sc1\n\ts_waitcnt vmcnt(0)" ::: "memory");
            if (tid == 0)
                __hip_atomic_store(go, 1, __ATOMIC_RELAXED, __HIP_MEMORY_SCOPE_AGENT);
        } else {
            for (;;) {
                int v = __hip_atomic_load(go, __ATOMIC_RELAXED, __HIP_MEMORY_SCOPE_AGENT);
                if (__all(v != 0)) break;
                __builtin_amdgcn_s_sleep(1);
            }
            // CU-local L1 invalidate (L2 already inv'd by this XCD's leader)
            asm volatile("buffer_inv sc0\n\ts_waitcnt vmcnt(0)" ::: "memory");
        }
    }
    __syncthreads();
}

__global__ void __launch_bounds__(512, 1)
rnn_coop(const float* __restrict__ x,
         const float* __restrict__ W_ih0, const float* __restrict__ b_ih0,
         const float* __restrict__ W_hh0, const float* __restrict__ b_hh0,
         const float* __restrict__ W_ih,  const float* __restrict__ b_ih,
         const float* __restrict__ W_hh,  const float* __restrict__ b_hh,
         const float* __restrict__ W_fc,  const float* __restrict__ b_fc,
         float* __restrict__ out, char* __restrict__ wsb)
{
    extern __shared__ char smem[];
    __shared__ int sh_slot;

    const int blk = blockIdx.x, tid = threadIdx.x;
    const int wave = tid >> 6, lane = tid & 63;
    const int lrow = lane & 15;
    const int kg8  = (lane >> 4) << 3;
    const int rb   = (lane >> 4) << 2;

    // physical XCD id — correctness-grade grouping for the barrier
    int myxcd;
    asm volatile("s_getreg_b32 %0, hwreg(HW_REG_XCC_ID)" : "=s"(myxcd));
    myxcd &= 7;

    if (tid == 0)
        sh_slot = __hip_atomic_fetch_add((int*)(wsb + CE_OFF) + myxcd, 1,
                                         __ATOMIC_RELAXED, __HIP_MEMORY_SCOPE_AGENT);

    // work mapping (placement-independent)
    const int stage = (blk & 7) >> 1;                       // 0..3
    const int tile  = (blk >> 3) | ((blk & 1) << 5);        // 0..63
    const int N0    = tile * 16;

    // ---- one-time: stage weight slices into LDS fragment images ----
    char* img_a = smem;
    char* img_b;
    char* img_fc = smem + 49152;
    if (stage == 0) {
        img_b = smem + 16384;
        stage_img(img_a, W_ih0, II, N0, tid);
        stage_img(img_b, W_hh0, HH, N0, tid);
        stage_img(img_fc, W_fc, HH, (tile & 31) * 16, tid);
    } else {
        img_b = smem + 32768;
        stage_img(img_a, W_ih + (size_t)(stage-1)*HH*HH, HH, N0, tid);
        stage_img(img_b, W_hh + (size_t)(stage-1)*HH*HH, HH, N0, tid);
    }

    const int bcol = N0 + lrow;
    float bi;
    if (stage == 0) bi = b_ih0[bcol] + b_hh0[bcol];
    else            bi = b_ih[(stage-1)*HH + bcol] + b_hh[(stage-1)*HH + bcol];

    // FC duty: stage-0 blocks, waves 0..3 (64 rows x 16 cols per block)
    const int fcol  = (tile & 31) * 16 + lrow;
    const int frow0 = (tile >> 5) * 64 + 16 * wave;
    const float fbias = (stage == 0) ? b_fc[fcol] : 0.f;

    const int r0row = 16 * wave + lrow;        // this wave's A row
    __bf16* hb = (__bf16*)wsb;

    __syncthreads();                  // LDS images + census slot written
    init_barrier(wsb, blk & 7, tid);  // census complete grid-wide
    const bool leader = (sh_slot == 0);

    // ---- pipelined tick loop ----
    for (int tk = 0; tk < TICKS; ++tk) {
        const int p = (tk + 1) & 1;             // read parity
        const int q = tk & 1;                   // write parity
        const int t = tk - stage;

        if (t >= 0 && t < TT) {
            f32x4 acc = {0.f,0.f,0.f,0.f};
            if (stage == 0) {
                const float* xa = x + (size_t)r0row * (TT*II) + (size_t)t * II + kg8;
                gemm1<II/32, 4>(xa, img_a, lane, acc);
                const __bf16* ha = hb + ((size_t)(p*4 + 0) * BB + r0row) * HH + kg8;
                gemm1<HH/32, 8>(ha, img_b, lane, acc);
            } else {
                const __bf16* a1 = hb + ((size_t)(p*4 + stage-1) * BB + r0row) * HH + kg8;
                gemm1<HH/32, 8>(a1, img_a, lane, acc);
                const __bf16* a2 = hb + ((size_t)(p*4 + stage) * BB + r0row) * HH + kg8;
                gemm1<HH/32, 8>(a2, img_b, lane, acc);
            }
            __bf16* hq = hb + (size_t)(q*4 + stage) * (BB*HH);
            #pragma unroll
            for (int j = 0; j < 4; ++j) {
                int m = 16 * wave + rb + j;
                store_h_wt(hq + (size_t)m*HH + bcol, tanh_fast(acc[j] + bi));
            }
        }

        if (stage == 0 && wave < 4) {
            const int t4 = tk - 4;
            if (t4 >= 0) {
                f32x4 fa = {0.f,0.f,0.f,0.f};
                const __bf16* ap = hb + ((size_t)(p*4 + 3) * BB + frow0 + lrow) * HH + kg8;
                gemm1<HH/32, 8>(ap, img_fc, lane, fa);
                #pragma unroll
                for (int j = 0; j < 4; ++j) {
                    int b = frow0 + rb + j;
                    store_f_wt(out + ((size_t)b*TT + t4)*OO + fcol, fa[j] + fbias);
                }
            }
        }

        if (tk < TICKS - 1)
            tick_sync(wsb, tk, blk, myxcd, leader, tid);
    }
}

extern "C" void kernel_launch(void* const* d_in, const int* in_sizes, int n_in,
                              void* d_out, int out_size, void* d_ws, size_t ws_size,
                              hipStream_t stream) {
    const float* x     = (const float*)d_in[0];
    const float* W_ih0 = (const float*)d_in[1];
    const float* b_ih0 = (const float*)d_in[2];
    const float* W_hh0 = (const float*)d_in[3];
    const float* b_hh0 = (const float*)d_in[4];
    const float* W_ih  = (const float*)d_in[5];
    const float* b_ih  = (const float*)d_in[6];
    const float* W_hh  = (const float*)d_in[7];
    const float* b_hh  = (const float*)d_in[8];
    const float* W_fc  = (const float*)d_in[9];
    const float* b_fc  = (const float*)d_in[10];
    float* outp = (float*)d_out;
    char*  wsp  = (char*)d_ws;

    if (ws_size < CNT_END) return;   // diagnostic gate

    static int lds_attr_set = 0;     // host-side only; idempotent
    if (!lds_attr_set) {
        hipFuncSetAttribute((const void*)rnn_coop,
                            hipFuncAttributeMaxDynamicSharedMemorySize, LDS_BYTES);
        lds_attr_set = 1;
    }

    // zero h double-buffer + all flags/counters (tick-indexed, used once each)
    hipMemsetAsync(d_ws, 0, CNT_END, stream);

    void* args[] = { &x, &W_ih0, &b_ih0, &W_hh0, &b_hh0,
                     &W_ih, &b_ih, &W_hh, &b_hh, &W_fc, &b_fc,
                     &outp, &wsp };
    hipLaunchCooperativeKernel((const void*)rnn_coop, dim3(256), dim3(512),
                               args, LDS_BYTES, stream);
}